// Round 1
// 390.231 us; speedup vs baseline: 1.0325x; 1.0325x over previous
//
#include <hip/hip_runtime.h>
#include <hip/hip_bf16.h>
#include <math.h>

// B=8, S=2048, D=512, U=512. fp32 in, fp32 out.
// d_out = context [8,2048,512] ++ attn [8,2048,2048]
// Round 3: all GEMMs moved to a 256x256-tile, BK=32, 4-deep-pipelined
// structure: counted vmcnt (never 0 in main loop), raw s_barrier (no
// compiler vmcnt(0) drain), T2-style LDS chunk swizzle both-sides, T5
// setprio around the 32-MFMA cluster. 8 waves/block, 128 KB LDS, 1 block/CU.

typedef __attribute__((ext_vector_type(8))) short short8;
typedef __attribute__((ext_vector_type(4))) float fp32x4;

#define S_DIM 2048
#define D_DIM 512
#define U_DIM 512
#define BATCH 8

#define GLOBAL_AS __attribute__((address_space(1)))
#define LDS_AS __attribute__((address_space(3)))

// RNE float->bf16 (finite inputs only)
__device__ __forceinline__ unsigned short f2bf(float f) {
    unsigned int u = __builtin_bit_cast(unsigned int, f);
    u += 0x7fffu + ((u >> 16) & 1u);
    return (unsigned short)(u >> 16);
}
__device__ __forceinline__ unsigned int pack2bf(float lo, float hi) {
    return ((unsigned int)f2bf(hi) << 16) | f2bf(lo);
}

// async global->LDS, 16 B per lane; LDS dest = wave-uniform base + lane*16
__device__ __forceinline__ void async_copy16(const unsigned short* g, unsigned short* l) {
    __builtin_amdgcn_global_load_lds((const GLOBAL_AS unsigned int*)(const void*)g,
                                     (LDS_AS unsigned int*)(void*)l, 16, 0, 0);
}

__device__ __forceinline__ void storeC(float* p, float v) { *p = v; }
__device__ __forceinline__ void storeC(unsigned short* p, float v) { *p = f2bf(v); }

// ---- deep-pipelined 256x256 NT GEMM: C[m][n] = scale * sum_k A[m][k]*B[n][k]
// A,B bf16 row-major (K contiguous). M,N multiples of 256, K multiple of 32,
// K >= 128 (prologue stages 3 tiles). 512 threads = 8 waves (2 M x 4 N),
// per-wave output 128x64, acc[8][4] fp32x4 = 128 VGPR.
//
// LDS: 4 pipeline stages x (A 256x32 + B 256x32) bf16 = 128 KB.
// Swizzle (both-sides, rule #21): within each 64 B row, physical 16 B chunk
//   = logical chunk ^ (row & 3). global_load_lds writes LDS linearly, so the
//   per-lane GLOBAL source is inverse-swizzled; ds_read applies the same XOR.
//   Linear layout would be an 8-way bank conflict on the b128 frag reads
//   (64 B row stride); swizzled is 4-way.
//
// Pipeline (per wave, per K-tile kt):
//   issue 4 global_load_lds for tile kt+3 into buf (kt+3)&3   [freed: its
//     last reader was iter kt-1, proven done by iter kt-1's trailing barrier]
//   12 ds_read_b128 from buf kt&3 (compiler schedules lgkmcnt interleave)
//   setprio(1); 32 MFMA; setprio(0)
//   s_waitcnt vmcnt(8)   -> tile kt+1 landed, tiles kt+2/kt+3 stay in flight
//   s_barrier            -> raw builtin: no compiler vmcnt(0) drain
template <typename CT>
__global__ __launch_bounds__(512, 2) void gemm_nt_256(
    const unsigned short* __restrict__ A, const unsigned short* __restrict__ B,
    CT* __restrict__ C, int lda, int ldb, int ldc, int K,
    long aBatch, long bBatch, long cBatch, float scale) {
    A += (long)blockIdx.z * aBatch;
    B += (long)blockIdx.z * bBatch;
    C += (long)blockIdx.z * cBatch;
    const int m0 = blockIdx.y * 256;
    const int n0 = blockIdx.x * 256;

    __shared__ unsigned short lds[4 * 2 * 256 * 32];  // 128 KB

    const int tid = threadIdx.x;
    const int w = tid >> 6, lane = tid & 63;
    const int wr = w >> 2, wc = w & 3;  // wave tile: rows wr*128, cols wc*64
    const int lm = lane & 15, quad = lane >> 4;

    // ---- staging addressing ----
    // Linear LDS bytes covered by this thread in a 16 KB operand tile:
    //   o = L*8192 + w*1024 + lane*16  ->  row = o>>6, chunk = (o>>4)&3
    // Source element must be the one whose SWIZZLED position is o:
    //   src chunk = chunk ^ (row & 3), row unchanged.
    const int srow = w * 16 + (lane >> 2);                  // L=1 adds 128
    const int schunk = (lane & 3) ^ ((lane >> 2) & 3);      // inverse-swizzled
    const unsigned short* aSrc0 = A + (long)(m0 + srow) * lda + schunk * 8;
    const unsigned short* aSrc1 = A + (long)(m0 + 128 + srow) * lda + schunk * 8;
    const unsigned short* bSrc0 = B + (long)(n0 + srow) * ldb + schunk * 8;
    const unsigned short* bSrc1 = B + (long)(n0 + 128 + srow) * ldb + schunk * 8;
    // wave-uniform LDS dest bases (ushort units); + buf*16384 per stage
    const int dstA0 = w * 512;
    const int dstA1 = 4096 + w * 512;
    const int dstB0 = 8192 + w * 512;
    const int dstB1 = 12288 + w * 512;

    // ---- swizzled read addressing (ushort units) ----
    // frag row = base + 16*i + lm; row&3 == lm&3, so physical chunk = quad^(lm&3)
    const int rchunk = (quad ^ (lm & 3)) * 8;
    const int aRd = (wr * 128 + lm) * 32 + rchunk;           // + i*512
    const int bRd = 8192 + (wc * 64 + lm) * 32 + rchunk;     // + j*512

    fp32x4 acc[8][4];
#pragma unroll
    for (int i = 0; i < 8; i++)
#pragma unroll
        for (int j = 0; j < 4; j++) acc[i][j] = {0.f, 0.f, 0.f, 0.f};

#define STAGE(kt, buf)                                           \
    do {                                                         \
        const long ko_ = (long)(kt) * 32;                        \
        async_copy16(aSrc0 + ko_, &lds[(buf) * 16384 + dstA0]);  \
        async_copy16(aSrc1 + ko_, &lds[(buf) * 16384 + dstA1]);  \
        async_copy16(bSrc0 + ko_, &lds[(buf) * 16384 + dstB0]);  \
        async_copy16(bSrc1 + ko_, &lds[(buf) * 16384 + dstB1]);  \
    } while (0)

    const int NT = K >> 5;
    STAGE(0, 0);
    STAGE(1, 1);
    STAGE(2, 2);
    asm volatile("s_waitcnt vmcnt(8)" ::: "memory");  // tile 0 landed
    __builtin_amdgcn_s_barrier();

    for (int kt = 0; kt < NT; ++kt) {
        const int buf = kt & 3;
        if (kt + 3 < NT) STAGE(kt + 3, (kt + 3) & 3);

        const unsigned short* la = &lds[buf * 16384 + aRd];
        const unsigned short* lb = &lds[buf * 16384 + bRd];
        short8 bfr[4], afr[8];
#pragma unroll
        for (int j = 0; j < 4; ++j) bfr[j] = *(const short8*)(lb + j * 512);
#pragma unroll
        for (int i = 0; i < 8; ++i) afr[i] = *(const short8*)(la + i * 512);

        __builtin_amdgcn_s_setprio(1);
#pragma unroll
        for (int i = 0; i < 8; ++i)
#pragma unroll
            for (int j = 0; j < 4; ++j)
                acc[i][j] = __builtin_amdgcn_mfma_f32_16x16x32_bf16(afr[i], bfr[j], acc[i][j], 0, 0, 0);
        __builtin_amdgcn_s_setprio(0);

        if (kt < NT - 1) {
            // tiles allowed to stay in flight past this point: kt+2..min(kt+3,NT-1)
            const int mx = (kt + 3 < NT - 1) ? (kt + 3) : (NT - 1);
            const int cnt = mx - (kt + 1);
            if (cnt >= 2)
                asm volatile("s_waitcnt vmcnt(8)" ::: "memory");
            else if (cnt == 1)
                asm volatile("s_waitcnt vmcnt(4)" ::: "memory");
            else
                asm volatile("s_waitcnt vmcnt(0)" ::: "memory");
            __builtin_amdgcn_s_barrier();
        }
    }
#undef STAGE

    // C/D layout: col = lane&15, row = quad*4 + reg (harness-verified)
#pragma unroll
    for (int i = 0; i < 8; ++i) {
        const int m = m0 + wr * 128 + i * 16 + quad * 4;
#pragma unroll
        for (int j = 0; j < 4; ++j) {
            const int n = n0 + wc * 64 + j * 16 + lm;
#pragma unroll
            for (int r = 0; r < 4; ++r)
                storeC(&C[(long)(m + r) * ldc + n], acc[i][j][r] * scale);
        }
    }
}

// ---- fallback NT GEMM (synchronous staging, fp32 A ok) for small-ws path ----
__device__ __forceinline__ void stage16(unsigned short* dst, const unsigned short* src) {
    *(short8*)(dst) = *(const short8*)(src);
    *(short8*)(dst + 8) = *(const short8*)(src + 8);
}
__device__ __forceinline__ void stage16(unsigned short* dst, const float* src) {
#pragma unroll
    for (int c = 0; c < 16; c += 4) {
        float4 f = *(const float4*)(src + c);
        dst[c + 0] = f2bf(f.x);
        dst[c + 1] = f2bf(f.y);
        dst[c + 2] = f2bf(f.z);
        dst[c + 3] = f2bf(f.w);
    }
}
template <typename AT, typename CT>
__global__ __launch_bounds__(256) void gemm_nt(
    const AT* __restrict__ A, const unsigned short* __restrict__ B, CT* __restrict__ C,
    int lda, int ldb, int ldc, int K,
    long aBatch, long bBatch, long cBatch, float scale) {
    const int tid = threadIdx.x;
    A += (long)blockIdx.z * aBatch;
    B += (long)blockIdx.z * bBatch;
    C += (long)blockIdx.z * cBatch;
    const int m0 = blockIdx.y * 128;
    const int n0 = blockIdx.x * 128;

    __shared__ unsigned short lsA[128 * 40];
    __shared__ unsigned short lsB[128 * 40];

    const int wave = tid >> 6, lane = tid & 63;
    const int wm = (wave & 1) * 64;
    const int wn = (wave >> 1) * 64;
    const int lm = lane & 15;
    const int quad = lane >> 4;
    const int sr = tid >> 1;
    const int sc = (tid & 1) * 16;

    fp32x4 acc[4][4];
#pragma unroll
    for (int i = 0; i < 4; i++)
#pragma unroll
        for (int j = 0; j < 4; j++) acc[i][j] = {0.f, 0.f, 0.f, 0.f};

    for (int k0 = 0; k0 < K; k0 += 32) {
        __syncthreads();
        stage16(&lsA[sr * 40 + sc], A + (long)(m0 + sr) * lda + k0 + sc);
        stage16(&lsB[sr * 40 + sc], B + (long)(n0 + sr) * ldb + k0 + sc);
        __syncthreads();

        short8 af[4], bf[4];
#pragma unroll
        for (int i = 0; i < 4; i++)
            af[i] = *(const short8*)&lsA[(wm + i * 16 + lm) * 40 + quad * 8];
#pragma unroll
        for (int j = 0; j < 4; j++)
            bf[j] = *(const short8*)&lsB[(wn + j * 16 + lm) * 40 + quad * 8];
#pragma unroll
        for (int i = 0; i < 4; i++)
#pragma unroll
            for (int j = 0; j < 4; j++)
                acc[i][j] = __builtin_amdgcn_mfma_f32_16x16x32_bf16(af[i], bf[j], acc[i][j], 0, 0, 0);
    }
#pragma unroll
    for (int i = 0; i < 4; i++)
#pragma unroll
        for (int j = 0; j < 4; j++) {
            const int m = m0 + wm + i * 16 + quad * 4;
            const int n = n0 + wn + j * 16 + lm;
#pragma unroll
            for (int r = 0; r < 4; r++)
                storeC(&C[(long)(m + r) * ldc + n], acc[i][j][r] * scale);
        }
}

// ---- X fp32 -> bf16 ----
__global__ __launch_bounds__(256) void convert_x(const float* __restrict__ X,
                                                 unsigned short* __restrict__ Xb) {
    const int i = blockIdx.x * 256 + threadIdx.x;
    float4 f = ((const float4*)X)[i];
    ((uint2*)Xb)[i] = make_uint2(pack2bf(f.x, f.y), pack2bf(f.z, f.w));
}

// ---- W [D,U] fp32 -> Wt [U,D] bf16 ----
__global__ __launch_bounds__(256) void transpose_w(const float* __restrict__ W,
                                                   unsigned short* __restrict__ Wt) {
    __shared__ float t[32][33];
    const int tx = threadIdx.x & 31, ty = threadIdx.x >> 5;
    const int d0 = blockIdx.y * 32, u0 = blockIdx.x * 32;
#pragma unroll
    for (int i = 0; i < 32; i += 8) t[ty + i][tx] = W[(long)(d0 + ty + i) * U_DIM + u0 + tx];
    __syncthreads();
#pragma unroll
    for (int i = 0; i < 32; i += 8)
        Wt[(long)(u0 + ty + i) * D_DIM + d0 + tx] = f2bf(t[tx][ty + i]);
}

// ---- V [S,U] bf16 -> Vt [U,S] bf16, per batch ----
__global__ __launch_bounds__(256) void transpose_v(const unsigned short* __restrict__ V,
                                                   unsigned short* __restrict__ Vt) {
    V += (long)blockIdx.z * S_DIM * U_DIM;
    Vt += (long)blockIdx.z * U_DIM * S_DIM;
    __shared__ unsigned short t[32][33];
    const int tx = threadIdx.x & 31, ty = threadIdx.x >> 5;
    const int s0 = blockIdx.y * 32, u0 = blockIdx.x * 32;
#pragma unroll
    for (int i = 0; i < 32; i += 8) t[ty + i][tx] = V[(long)(s0 + ty + i) * U_DIM + u0 + tx];
    __syncthreads();
#pragma unroll
    for (int i = 0; i < 32; i += 8)
        Vt[(long)(u0 + ty + i) * S_DIM + s0 + tx] = t[tx][ty + i];
}

// ---- row softmax in place + optional bf16 sidecar ----
__global__ __launch_bounds__(256) void softmax_rows(float* __restrict__ attn,
                                                    unsigned short* __restrict__ attn_bf) {
    float4* p = (float4*)(attn + (long)blockIdx.x * S_DIM);
    const int tid = threadIdx.x;
    const int lane = tid & 63, wave = tid >> 6;
    float4 a = p[tid];
    float4 b = p[tid + 256];

    float mx = fmaxf(fmaxf(fmaxf(a.x, a.y), fmaxf(a.z, a.w)),
                     fmaxf(fmaxf(b.x, b.y), fmaxf(b.z, b.w)));
#pragma unroll
    for (int off = 32; off > 0; off >>= 1) mx = fmaxf(mx, __shfl_down(mx, off));
    __shared__ float red[8];
    if (lane == 0) red[wave] = mx;
    __syncthreads();
    const float rowmax = fmaxf(fmaxf(red[0], red[1]), fmaxf(red[2], red[3]));

    a.x = __expf(a.x - rowmax); a.y = __expf(a.y - rowmax);
    a.z = __expf(a.z - rowmax); a.w = __expf(a.w - rowmax);
    b.x = __expf(b.x - rowmax); b.y = __expf(b.y - rowmax);
    b.z = __expf(b.z - rowmax); b.w = __expf(b.w - rowmax);
    float s = a.x + a.y + a.z + a.w + b.x + b.y + b.z + b.w;
#pragma unroll
    for (int off = 32; off > 0; off >>= 1) s += __shfl_down(s, off);
    if (lane == 0) red[4 + wave] = s;
    __syncthreads();
    const float inv = 1.0f / (red[4] + red[5] + red[6] + red[7]);

    a.x *= inv; a.y *= inv; a.z *= inv; a.w *= inv;
    b.x *= inv; b.y *= inv; b.z *= inv; b.w *= inv;
    p[tid] = a;
    p[tid + 256] = b;

    if (attn_bf) {
        uint2* q = (uint2*)(attn_bf + (long)blockIdx.x * S_DIM);
        q[tid]       = make_uint2(pack2bf(a.x, a.y), pack2bf(a.z, a.w));
        q[tid + 256] = make_uint2(pack2bf(b.x, b.y), pack2bf(b.z, b.w));
    }
}

extern "C" void kernel_launch(void* const* d_in, const int* in_sizes, int n_in,
                              void* d_out, int out_size, void* d_ws, size_t ws_size,
                              hipStream_t stream) {
    const float* X  = (const float*)d_in[0];
    const float* Wq = (const float*)d_in[1];
    const float* Wk = (const float*)d_in[2];
    const float* Wv = (const float*)d_in[3];

    float* ctx  = (float*)d_out;
    float* attn = (float*)d_out + (size_t)BATCH * S_DIM * U_DIM;

    const size_t MTOT = (size_t)BATCH * S_DIM;  // 16384
    // ws layout (ushort elems): Xb | Wt | QKV ; Vt aliases Xb (dead after QKV
    // gemm); attn_bf aliases QKV (dead after transpose_v), extends 16.8 MB past.
    unsigned short* Xb  = (unsigned short*)d_ws;          // 16 MB
    unsigned short* Wt  = Xb + MTOT * D_DIM;              // 1.5 MB
    unsigned short* QKV = Wt + (size_t)3 * U_DIM * D_DIM; // 48 MB
    unsigned short* Vt  = Xb;
    unsigned short* attn_bf = QKV;                        // 64 MB (aliases QKV)

    unsigned short* Q  = QKV;
    unsigned short* Km = QKV + MTOT * U_DIM;
    unsigned short* V  = QKV + 2 * MTOT * U_DIM;

    // peak ws need with bf16-attn sidecar: Xb + Wt + attn_bf
    const size_t need = (MTOT * D_DIM + (size_t)3 * U_DIM * D_DIM) * 2 +
                        (size_t)BATCH * S_DIM * S_DIM * 2;
    const bool fast = ws_size >= need;

    convert_x<<<dim3((unsigned)(MTOT * D_DIM / 4 / 256)), 256, 0, stream>>>(X, Xb);
    transpose_w<<<dim3(16, 16), 256, 0, stream>>>(Wq, Wt);
    transpose_w<<<dim3(16, 16), 256, 0, stream>>>(Wk, Wt + (size_t)U_DIM * D_DIM);
    transpose_w<<<dim3(16, 16), 256, 0, stream>>>(Wv, Wt + (size_t)2 * U_DIM * D_DIM);

    // QKV = X @ W: M=16384, N=512, K=512 (z over {q,k,v})
    gemm_nt_256<unsigned short><<<dim3(2, 64, 3), 512, 0, stream>>>(
        Xb, Wt, QKV, D_DIM, D_DIM, U_DIM, D_DIM,
        0L, (long)U_DIM * D_DIM, (long)MTOT * U_DIM, 1.0f);

    // scores = Q @ K^T * 1/sqrt(U): per batch M=N=2048, K=512
    const float scale = 1.0f / sqrtf((float)U_DIM);
    gemm_nt_256<float><<<dim3(8, 8, BATCH), 512, 0, stream>>>(
        Q, Km, attn, U_DIM, U_DIM, S_DIM, U_DIM,
        (long)S_DIM * U_DIM, (long)S_DIM * U_DIM, (long)S_DIM * S_DIM, scale);

    // V^T per batch (must precede softmax's attn_bf write over QKV region)
    transpose_v<<<dim3(16, 64, BATCH), 256, 0, stream>>>(V, Vt);

    // softmax in place (+ bf16 sidecar when ws permits)
    softmax_rows<<<dim3((unsigned)MTOT), 256, 0, stream>>>(attn, fast ? attn_bf : nullptr);

    // context = attn @ V: per batch M=2048, N=512, K=2048
    if (fast) {
        gemm_nt_256<float><<<dim3(2, 8, BATCH), 512, 0, stream>>>(
            attn_bf, Vt, ctx, S_DIM, S_DIM, U_DIM, S_DIM,
            (long)S_DIM * S_DIM, (long)U_DIM * S_DIM, (long)S_DIM * U_DIM, 1.0f);
    } else {
        gemm_nt<float, float><<<dim3(4, 16, BATCH), 256, 0, stream>>>(
            attn, Vt, ctx, S_DIM, S_DIM, U_DIM, S_DIM,
            (long)S_DIM * S_DIM, (long)U_DIM * S_DIM, (long)S_DIM * U_DIM, 1.0f);
    }
}

// Round 2
// 369.550 us; speedup vs baseline: 1.0902x; 1.0560x over previous
//
#include <hip/hip_runtime.h>
#include <hip/hip_bf16.h>
#include <math.h>

// B=8, S=2048, D=512, U=512. fp32 in, fp32 out.
// d_out = context [8,2048,512] ++ attn [8,2048,2048]
// Round 4: GEMM retuned for occupancy + grid shape.
//   256x128 tile, BK=32, 3-stage pipeline -> 72 KB LDS -> 2 blocks/CU
//   (16 waves/CU, vs round-3's 128 KB/1 block/CU = m132 failure mode).
//   Counted vmcnt(3) (never 0 mid-loop), raw s_barrier, both-sides chunk
//   swizzle, setprio around MFMA cluster. Grids now exact CU multiples:
//   QKV 768, scores 1024, context 256 (was 128 = half GPU idle).

typedef __attribute__((ext_vector_type(8))) short short8;
typedef __attribute__((ext_vector_type(4))) float fp32x4;

#define S_DIM 2048
#define D_DIM 512
#define U_DIM 512
#define BATCH 8

#define GLOBAL_AS __attribute__((address_space(1)))
#define LDS_AS __attribute__((address_space(3)))

// RNE float->bf16 (finite inputs only)
__device__ __forceinline__ unsigned short f2bf(float f) {
    unsigned int u = __builtin_bit_cast(unsigned int, f);
    u += 0x7fffu + ((u >> 16) & 1u);
    return (unsigned short)(u >> 16);
}
__device__ __forceinline__ unsigned int pack2bf(float lo, float hi) {
    return ((unsigned int)f2bf(hi) << 16) | f2bf(lo);
}

// async global->LDS, 16 B per lane; LDS dest = wave-uniform base + lane*16
__device__ __forceinline__ void async_copy16(const unsigned short* g, unsigned short* l) {
    __builtin_amdgcn_global_load_lds((const GLOBAL_AS unsigned int*)(const void*)g,
                                     (LDS_AS unsigned int*)(void*)l, 16, 0, 0);
}

__device__ __forceinline__ void storeC(float* p, float v) { *p = v; }
__device__ __forceinline__ void storeC(unsigned short* p, float v) { *p = f2bf(v); }

// ---- pipelined 256x128 NT GEMM: C[m][n] = scale * sum_k A[m][k]*B[n][k]
// A,B bf16 row-major (K contiguous). M mult of 256, N mult of 128, K mult
// of 32 (>=64). 512 threads = 8 waves (4M x 2N), per-wave 64x64 output,
// acc[4][4] fp32x4 = 64 VGPR; __launch_bounds__(512,4) caps VGPR at 128 so
// both LDS (72 KB) and VGPR allow 2 blocks/CU = 4 waves/SIMD.
//
// LDS: 3 stages x (A 256x32 + B 128x32) bf16 = 72 KB.
// Swizzle (both-sides, rule #21): within each 64 B row, physical 16 B chunk
//   = logical chunk ^ (row & 3). global_load_lds writes linearly, so the
//   per-lane GLOBAL source is inverse-swizzled; ds_read applies the same
//   XOR. Result: b128 frag reads spread uniformly over all 32 banks (8
//   lanes per 4-bank group = wave64 floor, throughput-conflict-free).
//
// Per K-tile kt: issue STAGE(kt+2) (3 loads) -> 8 ds_read_b128 from buf
// kt%3 -> setprio(1) 16 MFMA setprio(0) -> s_waitcnt vmcnt(3) (tile kt+1
// landed, kt+2 stays in flight) -> s_barrier. Barrier also proves all
// waves consumed buf kt%3 before iter kt+1 overwrites buf (kt+3)%3.
template <typename CT>
__global__ __launch_bounds__(512, 4) void gemm_nt_v2(
    const unsigned short* __restrict__ A, const unsigned short* __restrict__ B,
    CT* __restrict__ C, int lda, int ldb, int ldc, int K,
    long aBatch, long bBatch, long cBatch, float scale) {
    A += (long)blockIdx.z * aBatch;
    B += (long)blockIdx.z * bBatch;
    C += (long)blockIdx.z * cBatch;
    const int m0 = blockIdx.y * 256;
    const int n0 = blockIdx.x * 128;

    __shared__ unsigned short lds[3 * 12288];  // 72 KB

    const int tid = threadIdx.x;
    const int w = tid >> 6, lane = tid & 63;
    const int wr = w >> 1, wc = w & 1;  // wave tile: rows wr*64, cols wc*64
    const int lm = lane & 15, quad = lane >> 4;

    // staging: thread covers linear LDS bytes w*1024 + lane*16 of each 8 KB
    // half -> row = w*16 + lane/4, phys chunk = lane&3. Source chunk is
    // inverse-swizzled: (lane&3) ^ (row&3).
    const int srow = w * 16 + (lane >> 2);
    const int schunk = (lane & 3) ^ ((lane >> 2) & 3);
    const unsigned short* aSrc0 = A + (long)(m0 + srow) * lda + schunk * 8;
    const unsigned short* aSrc1 = A + (long)(m0 + 128 + srow) * lda + schunk * 8;
    const unsigned short* bSrc  = B + (long)(n0 + srow) * ldb + schunk * 8;
    const int dstA0 = w * 512;            // ushort units, wave-uniform
    const int dstA1 = 4096 + w * 512;
    const int dstB  = 8192 + w * 512;

    // swizzled read addressing: frag row = base + 16*i + lm -> row&3 == lm&3
    const int rchunk = (quad ^ (lm & 3)) * 8;
    const int aRd = (wr * 64 + lm) * 32 + rchunk;            // + i*512
    const int bRd = 8192 + (wc * 64 + lm) * 32 + rchunk;     // + j*512

    fp32x4 acc[4][4];
#pragma unroll
    for (int i = 0; i < 4; i++)
#pragma unroll
        for (int j = 0; j < 4; j++) acc[i][j] = {0.f, 0.f, 0.f, 0.f};

#define STAGE(kt, buf)                                          \
    do {                                                        \
        const long ko_ = (long)(kt) * 32;                       \
        const int b_ = (buf) * 12288;                           \
        async_copy16(aSrc0 + ko_, &lds[b_ + dstA0]);            \
        async_copy16(aSrc1 + ko_, &lds[b_ + dstA1]);            \
        async_copy16(bSrc + ko_, &lds[b_ + dstB]);              \
    } while (0)

    const int NT = K >> 5;
    STAGE(0, 0);
    STAGE(1, 1);
    asm volatile("s_waitcnt vmcnt(3)" ::: "memory");  // tile 0 landed
    __builtin_amdgcn_s_barrier();
    asm volatile("" ::: "memory");

    int bR = 0, bW = 2;
    for (int kt = 0; kt < NT; ++kt) {
        const bool more = (kt + 2) < NT;
        if (more) STAGE(kt + 2, bW);

        const unsigned short* la = &lds[bR * 12288 + aRd];
        const unsigned short* lb = &lds[bR * 12288 + bRd];
        short8 afr[4], bfr[4];
#pragma unroll
        for (int j = 0; j < 4; ++j) bfr[j] = *(const short8*)(lb + j * 512);
#pragma unroll
        for (int i = 0; i < 4; ++i) afr[i] = *(const short8*)(la + i * 512);

        __builtin_amdgcn_s_setprio(1);
#pragma unroll
        for (int i = 0; i < 4; ++i)
#pragma unroll
            for (int j = 0; j < 4; ++j)
                acc[i][j] = __builtin_amdgcn_mfma_f32_16x16x32_bf16(afr[i], bfr[j], acc[i][j], 0, 0, 0);
        __builtin_amdgcn_s_setprio(0);

        if (kt < NT - 1) {
            if (more)
                asm volatile("s_waitcnt vmcnt(3)" ::: "memory");
            else
                asm volatile("s_waitcnt vmcnt(0)" ::: "memory");
            __builtin_amdgcn_s_barrier();
            asm volatile("" ::: "memory");
        }
        bR = (bR == 2) ? 0 : bR + 1;
        bW = (bW == 2) ? 0 : bW + 1;
    }
#undef STAGE

    // C/D layout: col = lane&15, row = quad*4 + reg (harness-verified)
#pragma unroll
    for (int i = 0; i < 4; ++i) {
        const int m = m0 + wr * 64 + i * 16 + quad * 4;
#pragma unroll
        for (int j = 0; j < 4; ++j) {
            const int n = n0 + wc * 64 + j * 16 + lm;
#pragma unroll
            for (int r = 0; r < 4; ++r)
                storeC(&C[(long)(m + r) * ldc + n], acc[i][j][r] * scale);
        }
    }
}

// ---- fallback NT GEMM (synchronous staging, fp32 A ok) for small-ws path ----
__device__ __forceinline__ void stage16(unsigned short* dst, const unsigned short* src) {
    *(short8*)(dst) = *(const short8*)(src);
    *(short8*)(dst + 8) = *(const short8*)(src + 8);
}
__device__ __forceinline__ void stage16(unsigned short* dst, const float* src) {
#pragma unroll
    for (int c = 0; c < 16; c += 4) {
        float4 f = *(const float4*)(src + c);
        dst[c + 0] = f2bf(f.x);
        dst[c + 1] = f2bf(f.y);
        dst[c + 2] = f2bf(f.z);
        dst[c + 3] = f2bf(f.w);
    }
}
template <typename AT, typename CT>
__global__ __launch_bounds__(256) void gemm_nt(
    const AT* __restrict__ A, const unsigned short* __restrict__ B, CT* __restrict__ C,
    int lda, int ldb, int ldc, int K,
    long aBatch, long bBatch, long cBatch, float scale) {
    const int tid = threadIdx.x;
    A += (long)blockIdx.z * aBatch;
    B += (long)blockIdx.z * bBatch;
    C += (long)blockIdx.z * cBatch;
    const int m0 = blockIdx.y * 128;
    const int n0 = blockIdx.x * 128;

    __shared__ unsigned short lsA[128 * 40];
    __shared__ unsigned short lsB[128 * 40];

    const int wave = tid >> 6, lane = tid & 63;
    const int wm = (wave & 1) * 64;
    const int wn = (wave >> 1) * 64;
    const int lm = lane & 15;
    const int quad = lane >> 4;
    const int sr = tid >> 1;
    const int sc = (tid & 1) * 16;

    fp32x4 acc[4][4];
#pragma unroll
    for (int i = 0; i < 4; i++)
#pragma unroll
        for (int j = 0; j < 4; j++) acc[i][j] = {0.f, 0.f, 0.f, 0.f};

    for (int k0 = 0; k0 < K; k0 += 32) {
        __syncthreads();
        stage16(&lsA[sr * 40 + sc], A + (long)(m0 + sr) * lda + k0 + sc);
        stage16(&lsB[sr * 40 + sc], B + (long)(n0 + sr) * ldb + k0 + sc);
        __syncthreads();

        short8 af[4], bf[4];
#pragma unroll
        for (int i = 0; i < 4; i++)
            af[i] = *(const short8*)&lsA[(wm + i * 16 + lm) * 40 + quad * 8];
#pragma unroll
        for (int j = 0; j < 4; j++)
            bf[j] = *(const short8*)&lsB[(wn + j * 16 + lm) * 40 + quad * 8];
#pragma unroll
        for (int i = 0; i < 4; i++)
#pragma unroll
            for (int j = 0; j < 4; j++)
                acc[i][j] = __builtin_amdgcn_mfma_f32_16x16x32_bf16(af[i], bf[j], acc[i][j], 0, 0, 0);
    }
#pragma unroll
    for (int i = 0; i < 4; i++)
#pragma unroll
        for (int j = 0; j < 4; j++) {
            const int m = m0 + wm + i * 16 + quad * 4;
            const int n = n0 + wn + j * 16 + lm;
#pragma unroll
            for (int r = 0; r < 4; r++)
                storeC(&C[(long)(m + r) * ldc + n], acc[i][j][r] * scale);
        }
}

// ---- X fp32 -> bf16 ----
__global__ __launch_bounds__(256) void convert_x(const float* __restrict__ X,
                                                 unsigned short* __restrict__ Xb) {
    const int i = blockIdx.x * 256 + threadIdx.x;
    float4 f = ((const float4*)X)[i];
    ((uint2*)Xb)[i] = make_uint2(pack2bf(f.x, f.y), pack2bf(f.z, f.w));
}

// ---- W [D,U] fp32 -> Wt [U,D] bf16 ----
__global__ __launch_bounds__(256) void transpose_w(const float* __restrict__ W,
                                                   unsigned short* __restrict__ Wt) {
    __shared__ float t[32][33];
    const int tx = threadIdx.x & 31, ty = threadIdx.x >> 5;
    const int d0 = blockIdx.y * 32, u0 = blockIdx.x * 32;
#pragma unroll
    for (int i = 0; i < 32; i += 8) t[ty + i][tx] = W[(long)(d0 + ty + i) * U_DIM + u0 + tx];
    __syncthreads();
#pragma unroll
    for (int i = 0; i < 32; i += 8)
        Wt[(long)(u0 + ty + i) * D_DIM + d0 + tx] = f2bf(t[tx][ty + i]);
}

// ---- V [S,U] bf16 -> Vt [U,S] bf16, per batch ----
__global__ __launch_bounds__(256) void transpose_v(const unsigned short* __restrict__ V,
                                                   unsigned short* __restrict__ Vt) {
    V += (long)blockIdx.z * S_DIM * U_DIM;
    Vt += (long)blockIdx.z * U_DIM * S_DIM;
    __shared__ unsigned short t[32][33];
    const int tx = threadIdx.x & 31, ty = threadIdx.x >> 5;
    const int s0 = blockIdx.y * 32, u0 = blockIdx.x * 32;
#pragma unroll
    for (int i = 0; i < 32; i += 8) t[ty + i][tx] = V[(long)(s0 + ty + i) * U_DIM + u0 + tx];
    __syncthreads();
#pragma unroll
    for (int i = 0; i < 32; i += 8)
        Vt[(long)(u0 + ty + i) * S_DIM + s0 + tx] = t[tx][ty + i];
}

// ---- row softmax in place + optional bf16 sidecar ----
__global__ __launch_bounds__(256) void softmax_rows(float* __restrict__ attn,
                                                    unsigned short* __restrict__ attn_bf) {
    float4* p = (float4*)(attn + (long)blockIdx.x * S_DIM);
    const int tid = threadIdx.x;
    const int lane = tid & 63, wave = tid >> 6;
    float4 a = p[tid];
    float4 b = p[tid + 256];

    float mx = fmaxf(fmaxf(fmaxf(a.x, a.y), fmaxf(a.z, a.w)),
                     fmaxf(fmaxf(b.x, b.y), fmaxf(b.z, b.w)));
#pragma unroll
    for (int off = 32; off > 0; off >>= 1) mx = fmaxf(mx, __shfl_down(mx, off));
    __shared__ float red[8];
    if (lane == 0) red[wave] = mx;
    __syncthreads();
    const float rowmax = fmaxf(fmaxf(red[0], red[1]), fmaxf(red[2], red[3]));

    a.x = __expf(a.x - rowmax); a.y = __expf(a.y - rowmax);
    a.z = __expf(a.z - rowmax); a.w = __expf(a.w - rowmax);
    b.x = __expf(b.x - rowmax); b.y = __expf(b.y - rowmax);
    b.z = __expf(b.z - rowmax); b.w = __expf(b.w - rowmax);
    float s = a.x + a.y + a.z + a.w + b.x + b.y + b.z + b.w;
#pragma unroll
    for (int off = 32; off > 0; off >>= 1) s += __shfl_down(s, off);
    if (lane == 0) red[4 + wave] = s;
    __syncthreads();
    const float inv = 1.0f / (red[4] + red[5] + red[6] + red[7]);

    a.x *= inv; a.y *= inv; a.z *= inv; a.w *= inv;
    b.x *= inv; b.y *= inv; b.z *= inv; b.w *= inv;
    p[tid] = a;
    p[tid + 256] = b;

    if (attn_bf) {
        uint2* q = (uint2*)(attn_bf + (long)blockIdx.x * S_DIM);
        q[tid]       = make_uint2(pack2bf(a.x, a.y), pack2bf(a.z, a.w));
        q[tid + 256] = make_uint2(pack2bf(b.x, b.y), pack2bf(b.z, b.w));
    }
}

extern "C" void kernel_launch(void* const* d_in, const int* in_sizes, int n_in,
                              void* d_out, int out_size, void* d_ws, size_t ws_size,
                              hipStream_t stream) {
    const float* X  = (const float*)d_in[0];
    const float* Wq = (const float*)d_in[1];
    const float* Wk = (const float*)d_in[2];
    const float* Wv = (const float*)d_in[3];

    float* ctx  = (float*)d_out;
    float* attn = (float*)d_out + (size_t)BATCH * S_DIM * U_DIM;

    const size_t MTOT = (size_t)BATCH * S_DIM;  // 16384
    // ws layout (ushort elems): Xb | Wt | QKV ; Vt aliases Xb (dead after QKV
    // gemm); attn_bf aliases QKV (dead after transpose_v), extends 16.8 MB past.
    unsigned short* Xb  = (unsigned short*)d_ws;          // 16 MB
    unsigned short* Wt  = Xb + MTOT * D_DIM;              // 1.5 MB
    unsigned short* QKV = Wt + (size_t)3 * U_DIM * D_DIM; // 48 MB
    unsigned short* Vt  = Xb;
    unsigned short* attn_bf = QKV;                        // 64 MB (aliases QKV)

    unsigned short* Q  = QKV;
    unsigned short* Km = QKV + MTOT * U_DIM;
    unsigned short* V  = QKV + 2 * MTOT * U_DIM;

    // peak ws need with bf16-attn sidecar: Xb + Wt + attn_bf
    const size_t need = (MTOT * D_DIM + (size_t)3 * U_DIM * D_DIM) * 2 +
                        (size_t)BATCH * S_DIM * S_DIM * 2;
    const bool fast = ws_size >= need;

    convert_x<<<dim3((unsigned)(MTOT * D_DIM / 4 / 256)), 256, 0, stream>>>(X, Xb);
    transpose_w<<<dim3(16, 16), 256, 0, stream>>>(Wq, Wt);
    transpose_w<<<dim3(16, 16), 256, 0, stream>>>(Wk, Wt + (size_t)U_DIM * D_DIM);
    transpose_w<<<dim3(16, 16), 256, 0, stream>>>(Wv, Wt + (size_t)2 * U_DIM * D_DIM);

    // QKV = X @ W: M=16384, N=512, K=512 (z over {q,k,v}) -> 768 blocks (3.0 waves)
    gemm_nt_v2<unsigned short><<<dim3(4, 64, 3), 512, 0, stream>>>(
        Xb, Wt, QKV, D_DIM, D_DIM, U_DIM, D_DIM,
        0L, (long)U_DIM * D_DIM, (long)MTOT * U_DIM, 1.0f);

    // scores = Q @ K^T * 1/sqrt(U): per batch M=N=2048, K=512 -> 1024 blocks
    const float scale = 1.0f / sqrtf((float)U_DIM);
    gemm_nt_v2<float><<<dim3(16, 8, BATCH), 512, 0, stream>>>(
        Q, Km, attn, U_DIM, U_DIM, S_DIM, U_DIM,
        (long)S_DIM * U_DIM, (long)S_DIM * U_DIM, (long)S_DIM * S_DIM, scale);

    // V^T per batch (must precede softmax's attn_bf write over QKV region)
    transpose_v<<<dim3(16, 64, BATCH), 256, 0, stream>>>(V, Vt);

    // softmax in place (+ bf16 sidecar when ws permits)
    softmax_rows<<<dim3((unsigned)MTOT), 256, 0, stream>>>(attn, fast ? attn_bf : nullptr);

    // context = attn @ V: per batch M=2048, N=512, K=2048 -> 256 blocks (1.0 wave)
    if (fast) {
        gemm_nt_v2<float><<<dim3(4, 8, BATCH), 512, 0, stream>>>(
            attn_bf, Vt, ctx, S_DIM, S_DIM, U_DIM, S_DIM,
            (long)S_DIM * S_DIM, (long)U_DIM * S_DIM, (long)S_DIM * U_DIM, 1.0f);
    } else {
        gemm_nt<float, float><<<dim3(4, 16, BATCH), 256, 0, stream>>>(
            attn, Vt, ctx, S_DIM, S_DIM, U_DIM, S_DIM,
            (long)S_DIM * S_DIM, (long)U_DIM * S_DIM, (long)S_DIM * U_DIM, 1.0f);
    }
}

// Round 3
// 360.428 us; speedup vs baseline: 1.1178x; 1.0253x over previous
//
#include <hip/hip_runtime.h>
#include <hip/hip_bf16.h>
#include <math.h>

// B=8, S=2048, D=512, U=512. fp32 in, fp32 out.
// d_out = context [8,2048,512] ++ attn [8,2048,2048]
// Round 5:
//  - scores: v2 256x128-tile 3-stage counted-vmcnt kernel (2 blocks/CU,
//    1024-block grid = 2 exact dispatch rounds) + XCD-contiguous remap.
//  - QKV + context: new v3 128x128-tile 4-wave kernel, 48 KB LDS ->
//    3 blocks/CU, grids 1536 / 512 (exact rounds). Fixes round-4 context
//    grid (256 blocks = half-idle machine, no co-resident partner).
//  - T1 XCD swizzle in all pipelined GEMMs (grids all %8 == 0, bijective).

typedef __attribute__((ext_vector_type(8))) short short8;
typedef __attribute__((ext_vector_type(4))) float fp32x4;

#define S_DIM 2048
#define D_DIM 512
#define U_DIM 512
#define BATCH 8

#define GLOBAL_AS __attribute__((address_space(1)))
#define LDS_AS __attribute__((address_space(3)))

// RNE float->bf16 (finite inputs only)
__device__ __forceinline__ unsigned short f2bf(float f) {
    unsigned int u = __builtin_bit_cast(unsigned int, f);
    u += 0x7fffu + ((u >> 16) & 1u);
    return (unsigned short)(u >> 16);
}
__device__ __forceinline__ unsigned int pack2bf(float lo, float hi) {
    return ((unsigned int)f2bf(hi) << 16) | f2bf(lo);
}

// async global->LDS, 16 B per lane; LDS dest = wave-uniform base + lane*16
__device__ __forceinline__ void async_copy16(const unsigned short* g, unsigned short* l) {
    __builtin_amdgcn_global_load_lds((const GLOBAL_AS unsigned int*)(const void*)g,
                                     (LDS_AS unsigned int*)(void*)l, 16, 0, 0);
}

__device__ __forceinline__ void storeC(float* p, float v) { *p = v; }
__device__ __forceinline__ void storeC(unsigned short* p, float v) { *p = f2bf(v); }

// T1: XCD-contiguous remap of the flattened block id. Requires total
// block count % 8 == 0 (all our grids: 1024/1536/512). Consecutive
// logical tiles land on the same XCD -> operand-panel L2 reuse.
__device__ __forceinline__ void xcd_remap(int& bx, int& by, int& bz) {
    const unsigned gx = gridDim.x, gy = gridDim.y;
    const unsigned nb = gx * gy * gridDim.z;
    const unsigned id = blockIdx.x + gx * (blockIdx.y + gy * blockIdx.z);
    const unsigned cpx = nb >> 3;
    const unsigned swz = (id & 7) * cpx + (id >> 3);
    const unsigned pg = gx * gy;
    bz = swz / pg;
    const unsigned r = swz - bz * pg;
    by = r / gx;
    bx = r - by * gx;
}

// ---- pipelined 256x128 NT GEMM (8 waves, 2 blocks/CU) ----
// C[m][n] = scale * sum_k A[m][k]*B[n][k]; A,B bf16 row-major.
// M mult 256, N mult 128, K mult 32 (>=64). LDS 3 stages x 24 KB = 72 KB.
// Swizzle: within each 64 B row, phys 16 B chunk = logical chunk ^ (row&3),
// applied on both sides (inverse-swizzled global source for the linear
// global_load_lds write; same XOR on ds_read). Frag reads then spread
// 8 lanes/bank-quad = wave64 floor (throughput-conflict-free).
template <typename CT>
__global__ __launch_bounds__(512, 4) void gemm_nt_v2(
    const unsigned short* __restrict__ A, const unsigned short* __restrict__ B,
    CT* __restrict__ C, int lda, int ldb, int ldc, int K,
    long aBatch, long bBatch, long cBatch, float scale) {
    int bx, by, bz;
    xcd_remap(bx, by, bz);
    A += (long)bz * aBatch;
    B += (long)bz * bBatch;
    C += (long)bz * cBatch;
    const int m0 = by * 256;
    const int n0 = bx * 128;

    __shared__ unsigned short lds[3 * 12288];  // 72 KB

    const int tid = threadIdx.x;
    const int w = tid >> 6, lane = tid & 63;
    const int wr = w >> 1, wc = w & 1;  // wave tile: rows wr*64, cols wc*64
    const int lm = lane & 15, quad = lane >> 4;

    const int srow = w * 16 + (lane >> 2);
    const int schunk = (lane & 3) ^ ((lane >> 2) & 3);
    const unsigned short* aSrc0 = A + (long)(m0 + srow) * lda + schunk * 8;
    const unsigned short* aSrc1 = A + (long)(m0 + 128 + srow) * lda + schunk * 8;
    const unsigned short* bSrc  = B + (long)(n0 + srow) * ldb + schunk * 8;
    const int dstA0 = w * 512;  // ushort units, wave-uniform
    const int dstA1 = 4096 + w * 512;
    const int dstB  = 8192 + w * 512;

    const int rchunk = (quad ^ (lm & 3)) * 8;
    const int aRd = (wr * 64 + lm) * 32 + rchunk;         // + i*512
    const int bRd = 8192 + (wc * 64 + lm) * 32 + rchunk;  // + j*512

    fp32x4 acc[4][4];
#pragma unroll
    for (int i = 0; i < 4; i++)
#pragma unroll
        for (int j = 0; j < 4; j++) acc[i][j] = {0.f, 0.f, 0.f, 0.f};

#define STAGE(kt, buf)                                          \
    do {                                                        \
        const long ko_ = (long)(kt) * 32;                       \
        const int b_ = (buf) * 12288;                           \
        async_copy16(aSrc0 + ko_, &lds[b_ + dstA0]);            \
        async_copy16(aSrc1 + ko_, &lds[b_ + dstA1]);            \
        async_copy16(bSrc + ko_, &lds[b_ + dstB]);              \
    } while (0)

    const int NT = K >> 5;
    STAGE(0, 0);
    STAGE(1, 1);
    asm volatile("s_waitcnt vmcnt(3)" ::: "memory");  // tile 0 landed
    __builtin_amdgcn_s_barrier();
    asm volatile("" ::: "memory");

    int bR = 0, bW = 2;
    for (int kt = 0; kt < NT; ++kt) {
        const bool more = (kt + 2) < NT;
        if (more) STAGE(kt + 2, bW);

        const unsigned short* la = &lds[bR * 12288 + aRd];
        const unsigned short* lb = &lds[bR * 12288 + bRd];
        short8 afr[4], bfr[4];
#pragma unroll
        for (int j = 0; j < 4; ++j) bfr[j] = *(const short8*)(lb + j * 512);
#pragma unroll
        for (int i = 0; i < 4; ++i) afr[i] = *(const short8*)(la + i * 512);

        __builtin_amdgcn_s_setprio(1);
#pragma unroll
        for (int i = 0; i < 4; ++i)
#pragma unroll
            for (int j = 0; j < 4; ++j)
                acc[i][j] = __builtin_amdgcn_mfma_f32_16x16x32_bf16(afr[i], bfr[j], acc[i][j], 0, 0, 0);
        __builtin_amdgcn_s_setprio(0);

        if (kt < NT - 1) {
            if (more)
                asm volatile("s_waitcnt vmcnt(3)" ::: "memory");
            else
                asm volatile("s_waitcnt vmcnt(0)" ::: "memory");
            __builtin_amdgcn_s_barrier();
            asm volatile("" ::: "memory");
        }
        bR = (bR == 2) ? 0 : bR + 1;
        bW = (bW == 2) ? 0 : bW + 1;
    }
#undef STAGE

    // C/D layout: col = lane&15, row = quad*4 + reg
#pragma unroll
    for (int i = 0; i < 4; ++i) {
        const int m = m0 + wr * 64 + i * 16 + quad * 4;
#pragma unroll
        for (int j = 0; j < 4; ++j) {
            const int n = n0 + wc * 64 + j * 16 + lm;
#pragma unroll
            for (int r = 0; r < 4; ++r)
                storeC(&C[(long)(m + r) * ldc + n], acc[i][j][r] * scale);
        }
    }
}

// ---- pipelined 128x128 NT GEMM (4 waves, 3 blocks/CU) ----
// Same pipeline/swizzle as v2 but 48 KB LDS (3 x 16 KB stages) so three
// blocks co-reside per CU (9 waves/SIMD-ish occupancy class) — targets the
// QKV (M=16384) and context (K=2048, N=512) shapes whose 256x128 grids are
// ragged or under-filled. STAGE = 4 loads/thread-wave unit.
template <typename CT>
__global__ __launch_bounds__(256, 3) void gemm_nt_v3(
    const unsigned short* __restrict__ A, const unsigned short* __restrict__ B,
    CT* __restrict__ C, int lda, int ldb, int ldc, int K,
    long aBatch, long bBatch, long cBatch, float scale) {
    int bx, by, bz;
    xcd_remap(bx, by, bz);
    A += (long)bz * aBatch;
    B += (long)bz * bBatch;
    C += (long)bz * cBatch;
    const int m0 = by * 128;
    const int n0 = bx * 128;

    __shared__ unsigned short lds[3 * 8192];  // 48 KB

    const int tid = threadIdx.x;
    const int w = tid >> 6, lane = tid & 63;
    const int wr = w >> 1, wc = w & 1;
    const int lm = lane & 15, quad = lane >> 4;

    // staging: per stage, A tile 128x32 = two 4 KB units (loads L=0,1),
    // B likewise. Thread t covers linear bytes L*4096 + t*16 of each
    // operand region: row = L*64 + t/4, phys chunk = t&3; source chunk
    // inverse-swizzled by row&3 = (t/4)&3.
    const int srow = tid >> 2;                       // 0..63, +64 for L=1
    const int schunk = (tid & 3) ^ ((tid >> 2) & 3);
    const unsigned short* aSrc0 = A + (long)(m0 + srow) * lda + schunk * 8;
    const unsigned short* aSrc1 = A + (long)(m0 + 64 + srow) * lda + schunk * 8;
    const unsigned short* bSrc0 = B + (long)(n0 + srow) * ldb + schunk * 8;
    const unsigned short* bSrc1 = B + (long)(n0 + 64 + srow) * ldb + schunk * 8;
    const int dstA0 = w * 512;          // wave-uniform, ushort units
    const int dstA1 = 2048 + w * 512;
    const int dstB0 = 4096 + w * 512;
    const int dstB1 = 6144 + w * 512;

    const int rchunk = (quad ^ (lm & 3)) * 8;
    const int aRd = (wr * 64 + lm) * 32 + rchunk;         // + i*512
    const int bRd = 4096 + (wc * 64 + lm) * 32 + rchunk;  // + j*512

    fp32x4 acc[4][4];
#pragma unroll
    for (int i = 0; i < 4; i++)
#pragma unroll
        for (int j = 0; j < 4; j++) acc[i][j] = {0.f, 0.f, 0.f, 0.f};

#define STAGE3(kt, buf)                                         \
    do {                                                        \
        const long ko_ = (long)(kt) * 32;                       \
        const int b_ = (buf) * 8192;                            \
        async_copy16(aSrc0 + ko_, &lds[b_ + dstA0]);            \
        async_copy16(aSrc1 + ko_, &lds[b_ + dstA1]);            \
        async_copy16(bSrc0 + ko_, &lds[b_ + dstB0]);            \
        async_copy16(bSrc1 + ko_, &lds[b_ + dstB1]);            \
    } while (0)

    const int NT = K >> 5;
    STAGE3(0, 0);
    STAGE3(1, 1);
    asm volatile("s_waitcnt vmcnt(4)" ::: "memory");  // tile 0 landed
    __builtin_amdgcn_s_barrier();
    asm volatile("" ::: "memory");

    int bR = 0, bW = 2;
    for (int kt = 0; kt < NT; ++kt) {
        const bool more = (kt + 2) < NT;
        if (more) STAGE3(kt + 2, bW);

        const unsigned short* la = &lds[bR * 8192 + aRd];
        const unsigned short* lb = &lds[bR * 8192 + bRd];
        short8 afr[4], bfr[4];
#pragma unroll
        for (int j = 0; j < 4; ++j) bfr[j] = *(const short8*)(lb + j * 512);
#pragma unroll
        for (int i = 0; i < 4; ++i) afr[i] = *(const short8*)(la + i * 512);

        __builtin_amdgcn_s_setprio(1);
#pragma unroll
        for (int i = 0; i < 4; ++i)
#pragma unroll
            for (int j = 0; j < 4; ++j)
                acc[i][j] = __builtin_amdgcn_mfma_f32_16x16x32_bf16(afr[i], bfr[j], acc[i][j], 0, 0, 0);
        __builtin_amdgcn_s_setprio(0);

        if (kt < NT - 1) {
            if (more)
                asm volatile("s_waitcnt vmcnt(4)" ::: "memory");
            else
                asm volatile("s_waitcnt vmcnt(0)" ::: "memory");
            __builtin_amdgcn_s_barrier();
            asm volatile("" ::: "memory");
        }
        bR = (bR == 2) ? 0 : bR + 1;
        bW = (bW == 2) ? 0 : bW + 1;
    }
#undef STAGE3

#pragma unroll
    for (int i = 0; i < 4; ++i) {
        const int m = m0 + wr * 64 + i * 16 + quad * 4;
#pragma unroll
        for (int j = 0; j < 4; ++j) {
            const int n = n0 + wc * 64 + j * 16 + lm;
#pragma unroll
            for (int r = 0; r < 4; ++r)
                storeC(&C[(long)(m + r) * ldc + n], acc[i][j][r] * scale);
        }
    }
}

// ---- fallback NT GEMM (synchronous staging, fp32 A ok) for small-ws path ----
__device__ __forceinline__ void stage16(unsigned short* dst, const unsigned short* src) {
    *(short8*)(dst) = *(const short8*)(src);
    *(short8*)(dst + 8) = *(const short8*)(src + 8);
}
__device__ __forceinline__ void stage16(unsigned short* dst, const float* src) {
#pragma unroll
    for (int c = 0; c < 16; c += 4) {
        float4 f = *(const float4*)(src + c);
        dst[c + 0] = f2bf(f.x);
        dst[c + 1] = f2bf(f.y);
        dst[c + 2] = f2bf(f.z);
        dst[c + 3] = f2bf(f.w);
    }
}
template <typename AT, typename CT>
__global__ __launch_bounds__(256) void gemm_nt(
    const AT* __restrict__ A, const unsigned short* __restrict__ B, CT* __restrict__ C,
    int lda, int ldb, int ldc, int K,
    long aBatch, long bBatch, long cBatch, float scale) {
    const int tid = threadIdx.x;
    A += (long)blockIdx.z * aBatch;
    B += (long)blockIdx.z * bBatch;
    C += (long)blockIdx.z * cBatch;
    const int m0 = blockIdx.y * 128;
    const int n0 = blockIdx.x * 128;

    __shared__ unsigned short lsA[128 * 40];
    __shared__ unsigned short lsB[128 * 40];

    const int wave = tid >> 6, lane = tid & 63;
    const int wm = (wave & 1) * 64;
    const int wn = (wave >> 1) * 64;
    const int lm = lane & 15;
    const int quad = lane >> 4;
    const int sr = tid >> 1;
    const int sc = (tid & 1) * 16;

    fp32x4 acc[4][4];
#pragma unroll
    for (int i = 0; i < 4; i++)
#pragma unroll
        for (int j = 0; j < 4; j++) acc[i][j] = {0.f, 0.f, 0.f, 0.f};

    for (int k0 = 0; k0 < K; k0 += 32) {
        __syncthreads();
        stage16(&lsA[sr * 40 + sc], A + (long)(m0 + sr) * lda + k0 + sc);
        stage16(&lsB[sr * 40 + sc], B + (long)(n0 + sr) * ldb + k0 + sc);
        __syncthreads();

        short8 af[4], bf[4];
#pragma unroll
        for (int i = 0; i < 4; i++)
            af[i] = *(const short8*)&lsA[(wm + i * 16 + lm) * 40 + quad * 8];
#pragma unroll
        for (int j = 0; j < 4; j++)
            bf[j] = *(const short8*)&lsB[(wn + j * 16 + lm) * 40 + quad * 8];
#pragma unroll
        for (int i = 0; i < 4; i++)
#pragma unroll
            for (int j = 0; j < 4; j++)
                acc[i][j] = __builtin_amdgcn_mfma_f32_16x16x32_bf16(af[i], bf[j], acc[i][j], 0, 0, 0);
    }
#pragma unroll
    for (int i = 0; i < 4; i++)
#pragma unroll
        for (int j = 0; j < 4; j++) {
            const int m = m0 + wm + i * 16 + quad * 4;
            const int n = n0 + wn + j * 16 + lm;
#pragma unroll
            for (int r = 0; r < 4; r++)
                storeC(&C[(long)(m + r) * ldc + n], acc[i][j][r] * scale);
        }
}

// ---- X fp32 -> bf16 ----
__global__ __launch_bounds__(256) void convert_x(const float* __restrict__ X,
                                                 unsigned short* __restrict__ Xb) {
    const int i = blockIdx.x * 256 + threadIdx.x;
    float4 f = ((const float4*)X)[i];
    ((uint2*)Xb)[i] = make_uint2(pack2bf(f.x, f.y), pack2bf(f.z, f.w));
}

// ---- W [D,U] fp32 -> Wt [U,D] bf16 ----
__global__ __launch_bounds__(256) void transpose_w(const float* __restrict__ W,
                                                   unsigned short* __restrict__ Wt) {
    __shared__ float t[32][33];
    const int tx = threadIdx.x & 31, ty = threadIdx.x >> 5;
    const int d0 = blockIdx.y * 32, u0 = blockIdx.x * 32;
#pragma unroll
    for (int i = 0; i < 32; i += 8) t[ty + i][tx] = W[(long)(d0 + ty + i) * U_DIM + u0 + tx];
    __syncthreads();
#pragma unroll
    for (int i = 0; i < 32; i += 8)
        Wt[(long)(u0 + ty + i) * D_DIM + d0 + tx] = f2bf(t[tx][ty + i]);
}

// ---- V [S,U] bf16 -> Vt [U,S] bf16, per batch ----
__global__ __launch_bounds__(256) void transpose_v(const unsigned short* __restrict__ V,
                                                   unsigned short* __restrict__ Vt) {
    V += (long)blockIdx.z * S_DIM * U_DIM;
    Vt += (long)blockIdx.z * U_DIM * S_DIM;
    __shared__ unsigned short t[32][33];
    const int tx = threadIdx.x & 31, ty = threadIdx.x >> 5;
    const int s0 = blockIdx.y * 32, u0 = blockIdx.x * 32;
#pragma unroll
    for (int i = 0; i < 32; i += 8) t[ty + i][tx] = V[(long)(s0 + ty + i) * U_DIM + u0 + tx];
    __syncthreads();
#pragma unroll
    for (int i = 0; i < 32; i += 8)
        Vt[(long)(u0 + ty + i) * S_DIM + s0 + tx] = t[tx][ty + i];
}

// ---- row softmax in place + optional bf16 sidecar ----
__global__ __launch_bounds__(256) void softmax_rows(float* __restrict__ attn,
                                                    unsigned short* __restrict__ attn_bf) {
    float4* p = (float4*)(attn + (long)blockIdx.x * S_DIM);
    const int tid = threadIdx.x;
    const int lane = tid & 63, wave = tid >> 6;
    float4 a = p[tid];
    float4 b = p[tid + 256];

    float mx = fmaxf(fmaxf(fmaxf(a.x, a.y), fmaxf(a.z, a.w)),
                     fmaxf(fmaxf(b.x, b.y), fmaxf(b.z, b.w)));
#pragma unroll
    for (int off = 32; off > 0; off >>= 1) mx = fmaxf(mx, __shfl_down(mx, off));
    __shared__ float red[8];
    if (lane == 0) red[wave] = mx;
    __syncthreads();
    const float rowmax = fmaxf(fmaxf(red[0], red[1]), fmaxf(red[2], red[3]));

    a.x = __expf(a.x - rowmax); a.y = __expf(a.y - rowmax);
    a.z = __expf(a.z - rowmax); a.w = __expf(a.w - rowmax);
    b.x = __expf(b.x - rowmax); b.y = __expf(b.y - rowmax);
    b.z = __expf(b.z - rowmax); b.w = __expf(b.w - rowmax);
    float s = a.x + a.y + a.z + a.w + b.x + b.y + b.z + b.w;
#pragma unroll
    for (int off = 32; off > 0; off >>= 1) s += __shfl_down(s, off);
    if (lane == 0) red[4 + wave] = s;
    __syncthreads();
    const float inv = 1.0f / (red[4] + red[5] + red[6] + red[7]);

    a.x *= inv; a.y *= inv; a.z *= inv; a.w *= inv;
    b.x *= inv; b.y *= inv; b.z *= inv; b.w *= inv;
    p[tid] = a;
    p[tid + 256] = b;

    if (attn_bf) {
        uint2* q = (uint2*)(attn_bf + (long)blockIdx.x * S_DIM);
        q[tid]       = make_uint2(pack2bf(a.x, a.y), pack2bf(a.z, a.w));
        q[tid + 256] = make_uint2(pack2bf(b.x, b.y), pack2bf(b.z, b.w));
    }
}

extern "C" void kernel_launch(void* const* d_in, const int* in_sizes, int n_in,
                              void* d_out, int out_size, void* d_ws, size_t ws_size,
                              hipStream_t stream) {
    const float* X  = (const float*)d_in[0];
    const float* Wq = (const float*)d_in[1];
    const float* Wk = (const float*)d_in[2];
    const float* Wv = (const float*)d_in[3];

    float* ctx  = (float*)d_out;
    float* attn = (float*)d_out + (size_t)BATCH * S_DIM * U_DIM;

    const size_t MTOT = (size_t)BATCH * S_DIM;  // 16384
    unsigned short* Xb  = (unsigned short*)d_ws;          // 16 MB
    unsigned short* Wt  = Xb + MTOT * D_DIM;              // 1.5 MB
    unsigned short* QKV = Wt + (size_t)3 * U_DIM * D_DIM; // 48 MB
    unsigned short* Vt  = Xb;
    unsigned short* attn_bf = QKV;                        // 64 MB (aliases QKV)

    unsigned short* Q  = QKV;
    unsigned short* Km = QKV + MTOT * U_DIM;
    unsigned short* V  = QKV + 2 * MTOT * U_DIM;

    const size_t need = (MTOT * D_DIM + (size_t)3 * U_DIM * D_DIM) * 2 +
                        (size_t)BATCH * S_DIM * S_DIM * 2;
    const bool fast = ws_size >= need;

    convert_x<<<dim3((unsigned)(MTOT * D_DIM / 4 / 256)), 256, 0, stream>>>(X, Xb);
    transpose_w<<<dim3(16, 16), 256, 0, stream>>>(Wq, Wt);
    transpose_w<<<dim3(16, 16), 256, 0, stream>>>(Wk, Wt + (size_t)U_DIM * D_DIM);
    transpose_w<<<dim3(16, 16), 256, 0, stream>>>(Wv, Wt + (size_t)2 * U_DIM * D_DIM);

    // QKV = X @ W: M=16384, N=512, K=512 -> v3 128x128: 1536 blocks (2 exact
    // rounds at 3 blocks/CU).
    gemm_nt_v3<unsigned short><<<dim3(4, 128, 3), 256, 0, stream>>>(
        Xb, Wt, QKV, D_DIM, D_DIM, U_DIM, D_DIM,
        0L, (long)U_DIM * D_DIM, (long)MTOT * U_DIM, 1.0f);

    // scores = Q @ K^T * 1/sqrt(U): per batch M=N=2048, K=512 -> v2 256x128:
    // 1024 blocks (2 exact rounds at 2 blocks/CU).
    const float scale = 1.0f / sqrtf((float)U_DIM);
    gemm_nt_v2<float><<<dim3(16, 8, BATCH), 512, 0, stream>>>(
        Q, Km, attn, U_DIM, U_DIM, S_DIM, U_DIM,
        (long)S_DIM * U_DIM, (long)S_DIM * U_DIM, (long)S_DIM * S_DIM, scale);

    // V^T per batch (must precede softmax's attn_bf write over QKV region)
    transpose_v<<<dim3(16, 64, BATCH), 256, 0, stream>>>(V, Vt);

    // softmax in place (+ bf16 sidecar when ws permits)
    softmax_rows<<<dim3((unsigned)MTOT), 256, 0, stream>>>(attn, fast ? attn_bf : nullptr);

    // context = attn @ V: per batch M=2048, N=512, K=2048 -> v3 128x128:
    // 512 blocks (was 256 = half machine).
    if (fast) {
        gemm_nt_v3<float><<<dim3(4, 16, BATCH), 256, 0, stream>>>(
            attn_bf, Vt, ctx, S_DIM, S_DIM, U_DIM, S_DIM,
            (long)S_DIM * S_DIM, (long)U_DIM * S_DIM, (long)S_DIM * U_DIM, 1.0f);
    } else {
        gemm_nt<float, float><<<dim3(4, 16, BATCH), 256, 0, stream>>>(
            attn, Vt, ctx, S_DIM, S_DIM, U_DIM, S_DIM,
            (long)S_DIM * S_DIM, (long)U_DIM * S_DIM, (long)S_DIM * U_DIM, 1.0f);
    }
}

// Round 4
// 341.716 us; speedup vs baseline: 1.1791x; 1.0548x over previous
//
#include <hip/hip_runtime.h>
#include <hip/hip_bf16.h>
#include <math.h>

// B=8, S=2048, D=512, U=512. fp32 in, fp32 out.
// d_out = context [8,2048,512] ++ attn [8,2048,2048]
// Round 6 (plumbing, bitwise-identical outputs):
//  - Vt produced DIRECTLY as a GEMM (Vt[u,s] = sum_d Wv^T[u,d]*Xb[s,d]) ->
//    transpose_v and the V-slab round-trip eliminated.
//  - projection GEMM z=2 (Q,K only); transpose_w fused into one z=3 launch.
//  - ws relayout: Wt | Vt | QK | Xb, attn_bf aliases QK+Xb. need unchanged
//    (85,458,944 B, proven to fit).
// GEMM kernels unchanged from round 5 (256x128 v2 / 128x128 v3, 3-stage
// counted-vmcnt pipeline, both-sides chunk swizzle, setprio, XCD remap).

typedef __attribute__((ext_vector_type(8))) short short8;
typedef __attribute__((ext_vector_type(4))) float fp32x4;

#define S_DIM 2048
#define D_DIM 512
#define U_DIM 512
#define BATCH 8

#define GLOBAL_AS __attribute__((address_space(1)))
#define LDS_AS __attribute__((address_space(3)))

// RNE float->bf16 (finite inputs only)
__device__ __forceinline__ unsigned short f2bf(float f) {
    unsigned int u = __builtin_bit_cast(unsigned int, f);
    u += 0x7fffu + ((u >> 16) & 1u);
    return (unsigned short)(u >> 16);
}
__device__ __forceinline__ unsigned int pack2bf(float lo, float hi) {
    return ((unsigned int)f2bf(hi) << 16) | f2bf(lo);
}

// async global->LDS, 16 B per lane; LDS dest = wave-uniform base + lane*16
__device__ __forceinline__ void async_copy16(const unsigned short* g, unsigned short* l) {
    __builtin_amdgcn_global_load_lds((const GLOBAL_AS unsigned int*)(const void*)g,
                                     (LDS_AS unsigned int*)(void*)l, 16, 0, 0);
}

__device__ __forceinline__ void storeC(float* p, float v) { *p = v; }
__device__ __forceinline__ void storeC(unsigned short* p, float v) { *p = f2bf(v); }

// T1: XCD-contiguous remap of the flattened block id (grid total % 8 == 0).
__device__ __forceinline__ void xcd_remap(int& bx, int& by, int& bz) {
    const unsigned gx = gridDim.x, gy = gridDim.y;
    const unsigned nb = gx * gy * gridDim.z;
    const unsigned id = blockIdx.x + gx * (blockIdx.y + gy * blockIdx.z);
    const unsigned cpx = nb >> 3;
    const unsigned swz = (id & 7) * cpx + (id >> 3);
    const unsigned pg = gx * gy;
    bz = swz / pg;
    const unsigned r = swz - bz * pg;
    by = r / gx;
    bx = r - by * gx;
}

// ---- pipelined 256x128 NT GEMM (8 waves, 2 blocks/CU) ----
template <typename CT>
__global__ __launch_bounds__(512, 4) void gemm_nt_v2(
    const unsigned short* __restrict__ A, const unsigned short* __restrict__ B,
    CT* __restrict__ C, int lda, int ldb, int ldc, int K,
    long aBatch, long bBatch, long cBatch, float scale) {
    int bx, by, bz;
    xcd_remap(bx, by, bz);
    A += (long)bz * aBatch;
    B += (long)bz * bBatch;
    C += (long)bz * cBatch;
    const int m0 = by * 256;
    const int n0 = bx * 128;

    __shared__ unsigned short lds[3 * 12288];  // 72 KB

    const int tid = threadIdx.x;
    const int w = tid >> 6, lane = tid & 63;
    const int wr = w >> 1, wc = w & 1;
    const int lm = lane & 15, quad = lane >> 4;

    const int srow = w * 16 + (lane >> 2);
    const int schunk = (lane & 3) ^ ((lane >> 2) & 3);
    const unsigned short* aSrc0 = A + (long)(m0 + srow) * lda + schunk * 8;
    const unsigned short* aSrc1 = A + (long)(m0 + 128 + srow) * lda + schunk * 8;
    const unsigned short* bSrc  = B + (long)(n0 + srow) * ldb + schunk * 8;
    const int dstA0 = w * 512;
    const int dstA1 = 4096 + w * 512;
    const int dstB  = 8192 + w * 512;

    const int rchunk = (quad ^ (lm & 3)) * 8;
    const int aRd = (wr * 64 + lm) * 32 + rchunk;
    const int bRd = 8192 + (wc * 64 + lm) * 32 + rchunk;

    fp32x4 acc[4][4];
#pragma unroll
    for (int i = 0; i < 4; i++)
#pragma unroll
        for (int j = 0; j < 4; j++) acc[i][j] = {0.f, 0.f, 0.f, 0.f};

#define STAGE(kt, buf)                                          \
    do {                                                        \
        const long ko_ = (long)(kt) * 32;                       \
        const int b_ = (buf) * 12288;                           \
        async_copy16(aSrc0 + ko_, &lds[b_ + dstA0]);            \
        async_copy16(aSrc1 + ko_, &lds[b_ + dstA1]);            \
        async_copy16(bSrc + ko_, &lds[b_ + dstB]);              \
    } while (0)

    const int NT = K >> 5;
    STAGE(0, 0);
    STAGE(1, 1);
    asm volatile("s_waitcnt vmcnt(3)" ::: "memory");
    __builtin_amdgcn_s_barrier();
    asm volatile("" ::: "memory");

    int bR = 0, bW = 2;
    for (int kt = 0; kt < NT; ++kt) {
        const bool more = (kt + 2) < NT;
        if (more) STAGE(kt + 2, bW);

        const unsigned short* la = &lds[bR * 12288 + aRd];
        const unsigned short* lb = &lds[bR * 12288 + bRd];
        short8 afr[4], bfr[4];
#pragma unroll
        for (int j = 0; j < 4; ++j) bfr[j] = *(const short8*)(lb + j * 512);
#pragma unroll
        for (int i = 0; i < 4; ++i) afr[i] = *(const short8*)(la + i * 512);

        __builtin_amdgcn_s_setprio(1);
#pragma unroll
        for (int i = 0; i < 4; ++i)
#pragma unroll
            for (int j = 0; j < 4; ++j)
                acc[i][j] = __builtin_amdgcn_mfma_f32_16x16x32_bf16(afr[i], bfr[j], acc[i][j], 0, 0, 0);
        __builtin_amdgcn_s_setprio(0);

        if (kt < NT - 1) {
            if (more)
                asm volatile("s_waitcnt vmcnt(3)" ::: "memory");
            else
                asm volatile("s_waitcnt vmcnt(0)" ::: "memory");
            __builtin_amdgcn_s_barrier();
            asm volatile("" ::: "memory");
        }
        bR = (bR == 2) ? 0 : bR + 1;
        bW = (bW == 2) ? 0 : bW + 1;
    }
#undef STAGE

    // C/D layout: col = lane&15, row = quad*4 + reg
#pragma unroll
    for (int i = 0; i < 4; ++i) {
        const int m = m0 + wr * 64 + i * 16 + quad * 4;
#pragma unroll
        for (int j = 0; j < 4; ++j) {
            const int n = n0 + wc * 64 + j * 16 + lm;
#pragma unroll
            for (int r = 0; r < 4; ++r)
                storeC(&C[(long)(m + r) * ldc + n], acc[i][j][r] * scale);
        }
    }
}

// ---- pipelined 128x128 NT GEMM (4 waves, 3 blocks/CU) ----
template <typename CT>
__global__ __launch_bounds__(256, 3) void gemm_nt_v3(
    const unsigned short* __restrict__ A, const unsigned short* __restrict__ B,
    CT* __restrict__ C, int lda, int ldb, int ldc, int K,
    long aBatch, long bBatch, long cBatch, float scale) {
    int bx, by, bz;
    xcd_remap(bx, by, bz);
    A += (long)bz * aBatch;
    B += (long)bz * bBatch;
    C += (long)bz * cBatch;
    const int m0 = by * 128;
    const int n0 = bx * 128;

    __shared__ unsigned short lds[3 * 8192];  // 48 KB

    const int tid = threadIdx.x;
    const int w = tid >> 6, lane = tid & 63;
    const int wr = w >> 1, wc = w & 1;
    const int lm = lane & 15, quad = lane >> 4;

    const int srow = tid >> 2;
    const int schunk = (tid & 3) ^ ((tid >> 2) & 3);
    const unsigned short* aSrc0 = A + (long)(m0 + srow) * lda + schunk * 8;
    const unsigned short* aSrc1 = A + (long)(m0 + 64 + srow) * lda + schunk * 8;
    const unsigned short* bSrc0 = B + (long)(n0 + srow) * ldb + schunk * 8;
    const unsigned short* bSrc1 = B + (long)(n0 + 64 + srow) * ldb + schunk * 8;
    const int dstA0 = w * 512;
    const int dstA1 = 2048 + w * 512;
    const int dstB0 = 4096 + w * 512;
    const int dstB1 = 6144 + w * 512;

    const int rchunk = (quad ^ (lm & 3)) * 8;
    const int aRd = (wr * 64 + lm) * 32 + rchunk;
    const int bRd = 4096 + (wc * 64 + lm) * 32 + rchunk;

    fp32x4 acc[4][4];
#pragma unroll
    for (int i = 0; i < 4; i++)
#pragma unroll
        for (int j = 0; j < 4; j++) acc[i][j] = {0.f, 0.f, 0.f, 0.f};

#define STAGE3(kt, buf)                                         \
    do {                                                        \
        const long ko_ = (long)(kt) * 32;                       \
        const int b_ = (buf) * 8192;                            \
        async_copy16(aSrc0 + ko_, &lds[b_ + dstA0]);            \
        async_copy16(aSrc1 + ko_, &lds[b_ + dstA1]);            \
        async_copy16(bSrc0 + ko_, &lds[b_ + dstB0]);            \
        async_copy16(bSrc1 + ko_, &lds[b_ + dstB1]);            \
    } while (0)

    const int NT = K >> 5;
    STAGE3(0, 0);
    STAGE3(1, 1);
    asm volatile("s_waitcnt vmcnt(4)" ::: "memory");
    __builtin_amdgcn_s_barrier();
    asm volatile("" ::: "memory");

    int bR = 0, bW = 2;
    for (int kt = 0; kt < NT; ++kt) {
        const bool more = (kt + 2) < NT;
        if (more) STAGE3(kt + 2, bW);

        const unsigned short* la = &lds[bR * 8192 + aRd];
        const unsigned short* lb = &lds[bR * 8192 + bRd];
        short8 afr[4], bfr[4];
#pragma unroll
        for (int j = 0; j < 4; ++j) bfr[j] = *(const short8*)(lb + j * 512);
#pragma unroll
        for (int i = 0; i < 4; ++i) afr[i] = *(const short8*)(la + i * 512);

        __builtin_amdgcn_s_setprio(1);
#pragma unroll
        for (int i = 0; i < 4; ++i)
#pragma unroll
            for (int j = 0; j < 4; ++j)
                acc[i][j] = __builtin_amdgcn_mfma_f32_16x16x32_bf16(afr[i], bfr[j], acc[i][j], 0, 0, 0);
        __builtin_amdgcn_s_setprio(0);

        if (kt < NT - 1) {
            if (more)
                asm volatile("s_waitcnt vmcnt(4)" ::: "memory");
            else
                asm volatile("s_waitcnt vmcnt(0)" ::: "memory");
            __builtin_amdgcn_s_barrier();
            asm volatile("" ::: "memory");
        }
        bR = (bR == 2) ? 0 : bR + 1;
        bW = (bW == 2) ? 0 : bW + 1;
    }
#undef STAGE3

#pragma unroll
    for (int i = 0; i < 4; ++i) {
        const int m = m0 + wr * 64 + i * 16 + quad * 4;
#pragma unroll
        for (int j = 0; j < 4; ++j) {
            const int n = n0 + wc * 64 + j * 16 + lm;
#pragma unroll
            for (int r = 0; r < 4; ++r)
                storeC(&C[(long)(m + r) * ldc + n], acc[i][j][r] * scale);
        }
    }
}

// ---- fallback NT GEMM (synchronous staging, fp32 A ok) for small-ws path ----
__device__ __forceinline__ void stage16(unsigned short* dst, const unsigned short* src) {
    *(short8*)(dst) = *(const short8*)(src);
    *(short8*)(dst + 8) = *(const short8*)(src + 8);
}
__device__ __forceinline__ void stage16(unsigned short* dst, const float* src) {
#pragma unroll
    for (int c = 0; c < 16; c += 4) {
        float4 f = *(const float4*)(src + c);
        dst[c + 0] = f2bf(f.x);
        dst[c + 1] = f2bf(f.y);
        dst[c + 2] = f2bf(f.z);
        dst[c + 3] = f2bf(f.w);
    }
}
template <typename AT, typename CT>
__global__ __launch_bounds__(256) void gemm_nt(
    const AT* __restrict__ A, const unsigned short* __restrict__ B, CT* __restrict__ C,
    int lda, int ldb, int ldc, int K,
    long aBatch, long bBatch, long cBatch, float scale) {
    const int tid = threadIdx.x;
    A += (long)blockIdx.z * aBatch;
    B += (long)blockIdx.z * bBatch;
    C += (long)blockIdx.z * cBatch;
    const int m0 = blockIdx.y * 128;
    const int n0 = blockIdx.x * 128;

    __shared__ unsigned short lsA[128 * 40];
    __shared__ unsigned short lsB[128 * 40];

    const int wave = tid >> 6, lane = tid & 63;
    const int wm = (wave & 1) * 64;
    const int wn = (wave >> 1) * 64;
    const int lm = lane & 15;
    const int quad = lane >> 4;
    const int sr = tid >> 1;
    const int sc = (tid & 1) * 16;

    fp32x4 acc[4][4];
#pragma unroll
    for (int i = 0; i < 4; i++)
#pragma unroll
        for (int j = 0; j < 4; j++) acc[i][j] = {0.f, 0.f, 0.f, 0.f};

    for (int k0 = 0; k0 < K; k0 += 32) {
        __syncthreads();
        stage16(&lsA[sr * 40 + sc], A + (long)(m0 + sr) * lda + k0 + sc);
        stage16(&lsB[sr * 40 + sc], B + (long)(n0 + sr) * ldb + k0 + sc);
        __syncthreads();

        short8 af[4], bf[4];
#pragma unroll
        for (int i = 0; i < 4; i++)
            af[i] = *(const short8*)&lsA[(wm + i * 16 + lm) * 40 + quad * 8];
#pragma unroll
        for (int j = 0; j < 4; j++)
            bf[j] = *(const short8*)&lsB[(wn + j * 16 + lm) * 40 + quad * 8];
#pragma unroll
        for (int i = 0; i < 4; i++)
#pragma unroll
            for (int j = 0; j < 4; j++)
                acc[i][j] = __builtin_amdgcn_mfma_f32_16x16x32_bf16(af[i], bf[j], acc[i][j], 0, 0, 0);
    }
#pragma unroll
    for (int i = 0; i < 4; i++)
#pragma unroll
        for (int j = 0; j < 4; j++) {
            const int m = m0 + wm + i * 16 + quad * 4;
            const int n = n0 + wn + j * 16 + lm;
#pragma unroll
            for (int r = 0; r < 4; r++)
                storeC(&C[(long)(m + r) * ldc + n], acc[i][j][r] * scale);
        }
}

// ---- X fp32 -> bf16 ----
__global__ __launch_bounds__(256) void convert_x(const float* __restrict__ X,
                                                 unsigned short* __restrict__ Xb) {
    const int i = blockIdx.x * 256 + threadIdx.x;
    float4 f = ((const float4*)X)[i];
    ((uint2*)Xb)[i] = make_uint2(pack2bf(f.x, f.y), pack2bf(f.z, f.w));
}

// ---- W [D,U] fp32 -> Wt [U,D] bf16, z selects {Wq,Wk,Wv} ----
__global__ __launch_bounds__(256) void transpose_w3(const float* __restrict__ Wq,
                                                    const float* __restrict__ Wk,
                                                    const float* __restrict__ Wv,
                                                    unsigned short* __restrict__ Wt) {
    const float* W = (blockIdx.z == 0) ? Wq : (blockIdx.z == 1) ? Wk : Wv;
    unsigned short* o = Wt + (size_t)blockIdx.z * U_DIM * D_DIM;
    __shared__ float t[32][33];
    const int tx = threadIdx.x & 31, ty = threadIdx.x >> 5;
    const int d0 = blockIdx.y * 32, u0 = blockIdx.x * 32;
#pragma unroll
    for (int i = 0; i < 32; i += 8) t[ty + i][tx] = W[(long)(d0 + ty + i) * U_DIM + u0 + tx];
    __syncthreads();
#pragma unroll
    for (int i = 0; i < 32; i += 8)
        o[(long)(u0 + ty + i) * D_DIM + d0 + tx] = f2bf(t[tx][ty + i]);
}

// ---- V [S,U] bf16 -> Vt [U,S] bf16, per batch (fallback path only) ----
__global__ __launch_bounds__(256) void transpose_v(const unsigned short* __restrict__ V,
                                                   unsigned short* __restrict__ Vt) {
    V += (long)blockIdx.z * S_DIM * U_DIM;
    Vt += (long)blockIdx.z * U_DIM * S_DIM;
    __shared__ unsigned short t[32][33];
    const int tx = threadIdx.x & 31, ty = threadIdx.x >> 5;
    const int s0 = blockIdx.y * 32, u0 = blockIdx.x * 32;
#pragma unroll
    for (int i = 0; i < 32; i += 8) t[ty + i][tx] = V[(long)(s0 + ty + i) * U_DIM + u0 + tx];
    __syncthreads();
#pragma unroll
    for (int i = 0; i < 32; i += 8)
        Vt[(long)(u0 + ty + i) * S_DIM + s0 + tx] = t[tx][ty + i];
}

// ---- row softmax in place + optional bf16 sidecar ----
__global__ __launch_bounds__(256) void softmax_rows(float* __restrict__ attn,
                                                    unsigned short* __restrict__ attn_bf) {
    float4* p = (float4*)(attn + (long)blockIdx.x * S_DIM);
    const int tid = threadIdx.x;
    const int lane = tid & 63, wave = tid >> 6;
    float4 a = p[tid];
    float4 b = p[tid + 256];

    float mx = fmaxf(fmaxf(fmaxf(a.x, a.y), fmaxf(a.z, a.w)),
                     fmaxf(fmaxf(b.x, b.y), fmaxf(b.z, b.w)));
#pragma unroll
    for (int off = 32; off > 0; off >>= 1) mx = fmaxf(mx, __shfl_down(mx, off));
    __shared__ float red[8];
    if (lane == 0) red[wave] = mx;
    __syncthreads();
    const float rowmax = fmaxf(fmaxf(red[0], red[1]), fmaxf(red[2], red[3]));

    a.x = __expf(a.x - rowmax); a.y = __expf(a.y - rowmax);
    a.z = __expf(a.z - rowmax); a.w = __expf(a.w - rowmax);
    b.x = __expf(b.x - rowmax); b.y = __expf(b.y - rowmax);
    b.z = __expf(b.z - rowmax); b.w = __expf(b.w - rowmax);
    float s = a.x + a.y + a.z + a.w + b.x + b.y + b.z + b.w;
#pragma unroll
    for (int off = 32; off > 0; off >>= 1) s += __shfl_down(s, off);
    if (lane == 0) red[4 + wave] = s;
    __syncthreads();
    const float inv = 1.0f / (red[4] + red[5] + red[6] + red[7]);

    a.x *= inv; a.y *= inv; a.z *= inv; a.w *= inv;
    b.x *= inv; b.y *= inv; b.z *= inv; b.w *= inv;
    p[tid] = a;
    p[tid + 256] = b;

    if (attn_bf) {
        uint2* q = (uint2*)(attn_bf + (long)blockIdx.x * S_DIM);
        q[tid]       = make_uint2(pack2bf(a.x, a.y), pack2bf(a.z, a.w));
        q[tid + 256] = make_uint2(pack2bf(b.x, b.y), pack2bf(b.z, b.w));
    }
}

extern "C" void kernel_launch(void* const* d_in, const int* in_sizes, int n_in,
                              void* d_out, int out_size, void* d_ws, size_t ws_size,
                              hipStream_t stream) {
    const float* X  = (const float*)d_in[0];
    const float* Wq = (const float*)d_in[1];
    const float* Wk = (const float*)d_in[2];
    const float* Wv = (const float*)d_in[3];

    float* ctx  = (float*)d_out;
    float* attn = (float*)d_out + (size_t)BATCH * S_DIM * U_DIM;

    const size_t MTOT = (size_t)BATCH * S_DIM;            // 16384
    const size_t SLAB = MTOT * U_DIM;                     // 8,388,608 elems
    const size_t WSLB = (size_t)U_DIM * D_DIM;            // 262,144 elems
    const float scale = 1.0f / sqrtf((float)U_DIM);

    // fast ws layout (ushort elems): Wt(3) | Vt | QK(2) | Xb
    // attn_bf aliases QK..QK+4*SLAB (covers QK + Xb + 1 SLAB beyond; QK and
    // Xb are dead after the scores GEMM, before softmax writes attn_bf).
    unsigned short* Wt = (unsigned short*)d_ws;           // 3*WSLB
    unsigned short* Vt = Wt + 3 * WSLB;                   // SLAB (alive to end)
    unsigned short* QK = Vt + SLAB;                       // 2*SLAB (Q, K)
    unsigned short* Xb = QK + 2 * SLAB;                   // SLAB
    unsigned short* attn_bf = QK;                         // 4*SLAB span

    const size_t need = (3 * WSLB + SLAB + 4 * SLAB) * 2; // 85,458,944 B
    const bool fast = ws_size >= need;

    if (fast) {
        // X -> bf16
        convert_x<<<dim3((unsigned)(MTOT * D_DIM / 4 / 256)), 256, 0, stream>>>(X, Xb);
        // W^T x3 (one launch)
        transpose_w3<<<dim3(16, 16, 3), 256, 0, stream>>>(Wq, Wk, Wv, Wt);

        // Q,K projections: M=16384, N=512, K=512, z over {q,k} -> 1024 blocks
        gemm_nt_v3<unsigned short><<<dim3(4, 128, 2), 256, 0, stream>>>(
            Xb, Wt, QK, D_DIM, D_DIM, U_DIM, D_DIM,
            0L, (long)WSLB, (long)SLAB, 1.0f);

        // Vt[u,s] = sum_d Wv^T[u,d] * Xb[s,d]  (per batch M=512, N=2048,
        // K=512) -> 512 blocks. Bitwise-identical to projecting V then
        // transposing (same products, same accumulation order, one bf16
        // round), but no V slab and no transpose_v pass.
        gemm_nt_v3<unsigned short><<<dim3(16, 4, BATCH), 256, 0, stream>>>(
            Wt + 2 * WSLB, Xb, Vt, D_DIM, D_DIM, S_DIM, D_DIM,
            0L, (long)S_DIM * D_DIM, (long)U_DIM * S_DIM, 1.0f);

        // scores = Q @ K^T * 1/sqrt(U): per batch M=N=2048, K=512 -> 1024 blocks
        gemm_nt_v2<float><<<dim3(16, 8, BATCH), 512, 0, stream>>>(
            QK, QK + SLAB, attn, U_DIM, U_DIM, S_DIM, U_DIM,
            (long)S_DIM * U_DIM, (long)S_DIM * U_DIM, (long)S_DIM * S_DIM, scale);

        // softmax in place + bf16 sidecar (QK/Xb dead -> attn_bf may overwrite)
        softmax_rows<<<dim3((unsigned)MTOT), 256, 0, stream>>>(attn, attn_bf);

        // context = attn @ V: per batch M=2048, N=512, K=2048 -> 512 blocks
        gemm_nt_v3<float><<<dim3(4, 16, BATCH), 256, 0, stream>>>(
            attn_bf, Vt, ctx, S_DIM, S_DIM, U_DIM, S_DIM,
            (long)S_DIM * S_DIM, (long)U_DIM * S_DIM, (long)S_DIM * U_DIM, 1.0f);
    } else {
        // fallback: old layout/path (no bf16 sidecar; fp32-A context GEMM)
        unsigned short* fXb  = (unsigned short*)d_ws;           // 16 MB
        unsigned short* fWt  = fXb + MTOT * D_DIM;              // 1.5 MB
        unsigned short* fQKV = fWt + 3 * WSLB;                  // 48 MB
        unsigned short* fVt  = fXb;                             // alias
        unsigned short* fQ   = fQKV;
        unsigned short* fKm  = fQKV + SLAB;
        unsigned short* fV   = fQKV + 2 * SLAB;

        convert_x<<<dim3((unsigned)(MTOT * D_DIM / 4 / 256)), 256, 0, stream>>>(X, fXb);
        transpose_w3<<<dim3(16, 16, 3), 256, 0, stream>>>(Wq, Wk, Wv, fWt);

        gemm_nt_v3<unsigned short><<<dim3(4, 128, 3), 256, 0, stream>>>(
            fXb, fWt, fQKV, D_DIM, D_DIM, U_DIM, D_DIM,
            0L, (long)WSLB, (long)SLAB, 1.0f);

        gemm_nt_v2<float><<<dim3(16, 8, BATCH), 512, 0, stream>>>(
            fQ, fKm, attn, U_DIM, U_DIM, S_DIM, U_DIM,
            (long)S_DIM * U_DIM, (long)S_DIM * U_DIM, (long)S_DIM * S_DIM, scale);

        transpose_v<<<dim3(16, 64, BATCH), 256, 0, stream>>>(fV, fVt);

        softmax_rows<<<dim3((unsigned)MTOT), 256, 0, stream>>>(attn, nullptr);

        gemm_nt<float, float><<<dim3(4, 16, BATCH), 256, 0, stream>>>(
            attn, fVt, ctx, S_DIM, S_DIM, U_DIM, S_DIM,
            (long)S_DIM * S_DIM, (long)U_DIM * S_DIM, (long)S_DIM * U_DIM, 1.0f);
    }
}